// Round 7
// baseline (472.910 us; speedup 1.0000x reference)
//
#include <hip/hip_runtime.h>
#include <math.h>

// RoutingLayer fused via split-fp16 MFMA emulation of fp32 GEMM.
// routing = x@w_gate + noise*(softplus(x@w_noise)+0.01); out = scatter(softmax(top2)).
// x: 32768x2048 fp32, w_*: 2048x64 fp32, noise: 32768x64, out: 32768x64.
//
// R10: barrier-free main loop via WAVE-PRIVATE staging. R4-R9 all land at
// 146-176us with every pipe <25%: the per-chunk block-wide s_barrier
// locksteps all waves 64 times, so pipe times SUM (latency-bound). Now each
// wave owns ONE 32x32 tile (4 waves = gate-lo/hi, noise-lo/hi) and DMAs its
// OWN 4KB B-frags/chunk into its OWN dbuf LDS region; completion tracked by
// the wave's own vmcnt -> NO barrier in the loop, waves fully independent
// and de-phase freely (attn-like regime; setprio applies, m191).
// BM=32 -> grid 1024 -> 4 blocks/CU x 4 waves = 16 waves/CU (LDS 33KB).
// WAR on dbuf slot fenced by per-wave lgkmcnt(0) before re-issue.
// vmcnt: 8 VMEM/wave/chunk (4 DMA + 4 x float4), depth-2, vmcnt(8) waits.
// R8 lesson: plain reg-staging gets sunk by the compiler; the asm-volatile
// vmcnt fences pin the x-loads in their batch region here.

typedef _Float16 half8v __attribute__((ext_vector_type(8)));
typedef float f32x4  __attribute__((ext_vector_type(4)));
typedef float f32x16 __attribute__((ext_vector_type(16)));

constexpr int DIMK = 2048;
constexpr int NEXP = 64;
constexpr int BM   = 32;         // rows per block
constexpr int NCH  = DIMK / 32;  // 64 k-chunks of 32

__device__ __forceinline__ void async_load16(const void* g, void* l) {
    // global -> LDS DMA, 16B/lane; LDS dest = uniform base + lane*16
    __builtin_amdgcn_global_load_lds(
        (const __attribute__((address_space(1))) unsigned int*)g,
        (__attribute__((address_space(3))) unsigned int*)l, 16, 0, 0);
}

__device__ __forceinline__ bool gt_pair(float a, int ia, float b, int ib) {
    return (a > b) || (a == b && ia < ib);   // jax top_k: lower index wins ties
}

// ---- pre-kernel: split w' = 65536*[wg|wn] into 2 fp16 planes in 32x32x16
// B-frag order. Frag-block fb = c*16 + kh*8 + p*4 + nt  (1KB each, 1MB total):
// lane holds B[k = c*32 + kh*16 + (lane>>5)*8 + j][n' = nt*32 + (lane&31)]
// where nt 0,1 = w_gate cols 0..63 and nt 2,3 = w_noise cols 0..63.
__global__ __launch_bounds__(256)
void presplit_kernel(const float* __restrict__ wg, const float* __restrict__ wn,
                     _Float16* __restrict__ wsB)
{
    int gid  = blockIdx.x * 256 + threadIdx.x;   // 0..65535 = (fb, lane)
    int lane = gid & 63;
    int fb   = gid >> 6;          // 0..1023
    int nt   = fb & 3;
    int p    = (fb >> 2) & 1;
    int kh   = (fb >> 3) & 1;
    int c    = fb >> 4;
    const float* src = (nt < 2) ? (wg + nt * 32 + (lane & 31))
                                : (wn + (nt - 2) * 32 + (lane & 31));
    int kb = c * 32 + kh * 16 + ((lane >> 5) << 3);
    half8v hp;
    #pragma unroll
    for (int j = 0; j < 8; ++j) {
        float w = src[(size_t)(kb + j) * NEXP] * 65536.0f;
        _Float16 a = (_Float16)w;
        hp[j] = p ? (_Float16)(w - (float)a) : a;
    }
    *(half8v*)(wsB + (size_t)fb * 512 + lane * 8) = hp;
}

// ---- main kernel: 256 threads = 4 independent waves; wave w owns tile nt=w
// (32 rows x 32 cols of gate [w<2] or noise [w>=2]).
__global__ __launch_bounds__(256, 4)
void routing_mfma(const float* __restrict__ x, const _Float16* __restrict__ wsB,
                  const float* __restrict__ noise, float* __restrict__ out)
{
    __shared__ _Float16 Bp[4][2][4][64][8];   // 32 KB: [wave][buf][kh*2+p][lane][8]
    __shared__ float4   res[BM];              // 512 B

    const int tid  = threadIdx.x;
    const int lane = tid & 63;
    const int w    = tid >> 6;          // 0..3 = tile index nt
    const int m    = lane & 31;         // output col within tile / x row
    const int h    = lane >> 5;         // k-half selector within frag
    const int row0 = blockIdx.x * BM;

    f32x16 acc = {};                    // this wave's 32x32 tile
    float4 ra[2][4];                    // raw x double-buffer (slot literal)

    // A-frag source: lane holds A[row = m][k = c*32 + kh*16 + h*8 + j]
    const float* xp = x + (size_t)(row0 + m) * DIMK + h * 8;

    auto issue_B = [&](int c, int buf) {
        #pragma unroll
        for (int kh = 0; kh < 2; ++kh)
            #pragma unroll
            for (int p = 0; p < 2; ++p) {
                int fb = c * 16 + kh * 8 + p * 4 + w;
                async_load16(wsB + (size_t)fb * 512 + lane * 8,
                             &Bp[w][buf][kh * 2 + p][0][0]);
            }
    };

#define ISSUE_X(C, S)                                            \
    {   const float* p_ = xp + (C) * 32;                         \
        ra[S][0] = *(const float4*)(p_);                         \
        ra[S][1] = *(const float4*)(p_ + 4);                     \
        ra[S][2] = *(const float4*)(p_ + 16);                    \
        ra[S][3] = *(const float4*)(p_ + 20);  }

#define FENCE() asm volatile("" ::: "memory")

    // One chunk, wave-local. 8 VMEM ops per wave per STEP (4 DMA + 4 float4);
    // vmcnt(8) retires batch C while C+1 stays in flight. lgkmcnt(0) after
    // the ds_reads makes the dbuf slot safe to overwrite (WAR) before
    // issuing batch C+2 into it. NO s_barrier anywhere in the loop.
#define STEP(C, SLOT, ISS, WN)                                               \
    {                                                                        \
        asm volatile("s_waitcnt vmcnt(" #WN ")" ::: "memory");               \
        half8v bf[2][2];                                                     \
        _Pragma("unroll")                                                    \
        for (int kh = 0; kh < 2; ++kh)                                       \
            _Pragma("unroll")                                                \
            for (int p = 0; p < 2; ++p)                                      \
                bf[kh][p] = *(const half8v*)&Bp[w][SLOT][kh * 2 + p][lane][0];\
        half8v afH[2], afL[2];                                               \
        _Pragma("unroll")                                                    \
        for (int kh = 0; kh < 2; ++kh) {                                     \
            float4 u = ra[SLOT][kh * 2];                                     \
            float4 v = ra[SLOT][kh * 2 + 1];                                 \
            float f0 = u.x * 1024.f, f1 = u.y * 1024.f;                      \
            float f2 = u.z * 1024.f, f3 = u.w * 1024.f;                      \
            float f4 = v.x * 1024.f, f5 = v.y * 1024.f;                      \
            float f6 = v.z * 1024.f, f7 = v.w * 1024.f;                      \
            _Float16 a0=(_Float16)f0, a1=(_Float16)f1, a2=(_Float16)f2,      \
                     a3=(_Float16)f3, a4=(_Float16)f4, a5=(_Float16)f5,      \
                     a6=(_Float16)f6, a7=(_Float16)f7;                       \
            afH[kh][0]=a0; afH[kh][1]=a1; afH[kh][2]=a2; afH[kh][3]=a3;      \
            afH[kh][4]=a4; afH[kh][5]=a5; afH[kh][6]=a6; afH[kh][7]=a7;      \
            afL[kh][0]=(_Float16)(f0-(float)a0);                             \
            afL[kh][1]=(_Float16)(f1-(float)a1);                             \
            afL[kh][2]=(_Float16)(f2-(float)a2);                             \
            afL[kh][3]=(_Float16)(f3-(float)a3);                             \
            afL[kh][4]=(_Float16)(f4-(float)a4);                             \
            afL[kh][5]=(_Float16)(f5-(float)a5);                             \
            afL[kh][6]=(_Float16)(f6-(float)a6);                             \
            afL[kh][7]=(_Float16)(f7-(float)a7);                             \
        }                                                                    \
        asm volatile("s_waitcnt lgkmcnt(0)" ::: "memory");                   \
        if (ISS) { issue_B((C) + 2, SLOT); ISSUE_X((C) + 2, SLOT); }         \
        __builtin_amdgcn_s_setprio(1);                                       \
        _Pragma("unroll")                                                    \
        for (int kh = 0; kh < 2; ++kh) {                                     \
            acc = __builtin_amdgcn_mfma_f32_32x32x16_f16(                    \
                afH[kh], bf[kh][0], acc, 0, 0, 0);                           \
            acc = __builtin_amdgcn_mfma_f32_32x32x16_f16(                    \
                afH[kh], bf[kh][1], acc, 0, 0, 0);                           \
            acc = __builtin_amdgcn_mfma_f32_32x32x16_f16(                    \
                afL[kh], bf[kh][0], acc, 0, 0, 0);                           \
        }                                                                    \
        __builtin_amdgcn_s_setprio(0);                                       \
    }

    // Prologue: batches 0,1 (fence keeps batch issue-order for vmcnt math)
    issue_B(0, 0);
    ISSUE_X(0, 0);
    FENCE();
    issue_B(1, 1);
    ISSUE_X(1, 1);

    #pragma unroll 1
    for (int c = 0; c < NCH - 4; c += 2) {
        STEP(c + 0, 0, 1, 8)
        STEP(c + 1, 1, 1, 8)
    }
    STEP(NCH - 4, 0, 1, 8)    // c=60: issues batch 62
    STEP(NCH - 3, 1, 1, 8)    // c=61: issues batch 63
    STEP(NCH - 2, 0, 0, 8)    // c=62: outstanding {62,63} -> retire 62
    STEP(NCH - 1, 1, 0, 0)    // c=63: drain

#undef STEP
#undef ISSUE_X
#undef FENCE

    // ---- epilogue ----
    // 32x32 C/D layout: col = lane&31, row = (reg&3) + 8*(reg>>2) + 4*(lane>>5).
    // Write scaled tile into own LDS region (reuse Bp[w], stride-33 pad),
    // one barrier, then per-thread routing-combine + top2 + scatter.
    const float s = 0x1p-26f;
    {
        float* scr = (float*)&Bp[w][0][0][0][0];   // 8 KB region, use 4.2 KB
        #pragma unroll
        for (int reg = 0; reg < 16; ++reg) {
            int r = (reg & 3) + 8 * (reg >> 2) + 4 * h;   // 0..31
            scr[r * 33 + m] = acc[reg] * s;
        }
    }
    __syncthreads();

    {
        int r  = tid >> 3;           // 0..31: row within block
        int s8 = tid & 7;            // 8-expert segment
        const float* gsrc = (const float*)&Bp[s8 >> 2][0][0][0][0];
        const float* nsrc = (const float*)&Bp[2 + (s8 >> 2)][0][0][0][0];
        int cs = (s8 * 8) & 31;
        float4 z0 = *(const float4*)(noise + (size_t)(row0 + r) * NEXP + s8 * 8);
        float4 z1 = *(const float4*)(noise + (size_t)(row0 + r) * NEXP + s8 * 8 + 4);
        float zz[8] = {z0.x, z0.y, z0.z, z0.w, z1.x, z1.y, z1.z, z1.w};
        float v1 = -INFINITY, v2 = -INFINITY; int i1 = 0x7ffffffe, i2 = 0x7fffffff;
        #pragma unroll
        for (int j = 0; j < 8; ++j) {
            float gate = gsrc[r * 33 + cs + j];
            float nv   = nsrc[r * 33 + cs + j];
            float sp   = fmaxf(nv, 0.f) + log1pf(expf(-fabsf(nv)));
            float vv   = gate + zz[j] * (sp + 0.01f);
            int   e    = s8 * 8 + j;
            if (gt_pair(vv, e, v1, i1)) { v2 = v1; i2 = i1; v1 = vv; i1 = e; }
            else if (gt_pair(vv, e, v2, i2)) { v2 = vv; i2 = e; }
        }
        #pragma unroll
        for (int mm = 1; mm <= 4; mm <<= 1) {    // butterfly over the 8-lane group
            float b1 = __shfl_xor(v1, mm); int ib1 = __shfl_xor(i1, mm);
            float b2 = __shfl_xor(v2, mm); int ib2 = __shfl_xor(i2, mm);
            if (gt_pair(b1, ib1, v1, i1)) {
                float o1 = v1; int oi1 = i1;
                v1 = b1; i1 = ib1;
                if (gt_pair(b2, ib2, o1, oi1)) { v2 = b2; i2 = ib2; }
                else                           { v2 = o1; i2 = oi1; }
            } else if (gt_pair(b1, ib1, v2, i2)) {
                v2 = b1; i2 = ib1;
            }
        }
        if (s8 == 0) {
            float t  = expf(v2 - v1);     // <= 1
            float g1 = 1.f / (1.f + t);
            res[r] = make_float4(g1, __int_as_float(i1),
                                 t * g1, __int_as_float(i2));
        }
    }
    __syncthreads();

    {   // write full 32x64 out tile: thread -> row tid>>3, 8-col segment
        int rr  = tid >> 3;
        int seg = tid & 7;
        float4 rv = res[rr];
        float g1 = rv.x, g2 = rv.z;
        int   j1 = __float_as_int(rv.y), j2 = __float_as_int(rv.w);
        float* op = out + (size_t)(row0 + rr) * NEXP + seg * 8;
        #pragma unroll
        for (int qq = 0; qq < 2; ++qq) {
            int e0 = seg * 8 + qq * 4;
            float4 o;
            o.x = (e0 + 0 == j1) ? g1 : ((e0 + 0 == j2) ? g2 : 0.f);
            o.y = (e0 + 1 == j1) ? g1 : ((e0 + 1 == j2) ? g2 : 0.f);
            o.z = (e0 + 2 == j1) ? g1 : ((e0 + 2 == j2) ? g2 : 0.f);
            o.w = (e0 + 3 == j1) ? g1 : ((e0 + 3 == j2) ? g2 : 0.f);
            *(float4*)(op + qq * 4) = o;
        }
    }
}

extern "C" void kernel_launch(void* const* d_in, const int* in_sizes, int n_in,
                              void* d_out, int out_size, void* d_ws, size_t ws_size,
                              hipStream_t stream) {
    const float* x     = (const float*)d_in[0];
    const float* wg    = (const float*)d_in[1];
    const float* wn    = (const float*)d_in[2];
    const float* noise = (const float*)d_in[3];
    float* out = (float*)d_out;
    _Float16* wsB = (_Float16*)d_ws;   // needs 1024 * 1KB = 1 MB

    presplit_kernel<<<dim3(256), 256, 0, stream>>>(wg, wn, wsB);

    const int Brows = in_sizes[0] / DIMK;          // 32768
    dim3 grid(Brows / BM);                         // 1024 blocks -> 4/CU, 16 waves/CU
    routing_mfma<<<grid, 256, 0, stream>>>(x, wsB, noise, out);
}

// Round 8
// 399.776 us; speedup vs baseline: 1.1829x; 1.1829x over previous
//
#include <hip/hip_runtime.h>
#include <math.h>

// RoutingLayer fused via split-fp16 MFMA emulation of fp32 GEMM.
// routing = x@w_gate + noise*(softplus(x@w_noise)+0.01); out = scatter(softmax(top2)).
// x: 32768x2048 fp32, w_*: 2048x64 fp32, noise: 32768x64, out: 32768x64.
//
// R11: consolidation of R4-R10 evidence.
//  - Perf tracked occupancy + VMEM instr count/contiguity, NOT barriers (R10
//    barrier-free regressed) and NOT pipeline depth (R5 null).
//  - x staged via global_load_lds (contiguous 1KB instrs, compiler can't sink
//    it -- R8 lesson) with XOR-swizzled per-lane GLOBAL source so the fp32
//    fragment ds_read_b128s are <=4-way conflicted (not 32-way).
//  - fp32->split-fp16 conversion IN REGISTERS per use (kills R4's A-plane
//    LDS write+read round trip).
//  - 512-thr blocks (8 waves = 2 row-groups x 4 col-tiles), BM=64, 48KB LDS
//    (dbuf x 16KB + dbuf B 32KB, reused as epilogue scratch) -> 2 blocks/CU
//    = 16 waves/CU (R6 lesson).
//  - ONE __syncthreads per chunk; DMAs for c+2 issued right after it ->
//    every load has a full chunk (~2000cy >> 900cy HBM) of flight time, so
//    the barrier's vmcnt(0) drain is free (R5/R7 evidence). No inline asm.
//  - 32x32x16 MFMA (R9 fragment math, refcheck-passed).

typedef _Float16 half8v __attribute__((ext_vector_type(8)));
typedef float f32x16 __attribute__((ext_vector_type(16)));

constexpr int DIMK = 2048;
constexpr int NEXP = 64;
constexpr int BM   = 64;         // rows per block
constexpr int NCH  = DIMK / 32;  // 64 k-chunks of 32

__device__ __forceinline__ void async_load16(const void* g, void* l) {
    // global -> LDS DMA, 16B/lane; LDS dest = uniform base + lane*16,
    // GLOBAL source is per-lane (enables source-side swizzling, m173).
    __builtin_amdgcn_global_load_lds(
        (const __attribute__((address_space(1))) unsigned int*)g,
        (__attribute__((address_space(3))) unsigned int*)l, 16, 0, 0);
}

__device__ __forceinline__ bool gt_pair(float a, int ia, float b, int ib) {
    return (a > b) || (a == b && ia < ib);   // jax top_k: lower index wins ties
}

// ---- pre-kernel: split w' = 65536*[wg|wn] into 2 fp16 planes in 32x32x16
// B-frag order. Frag-block fb = c*16 + kh*8 + p*4 + nt  (1KB each, 1MB total):
// lane holds B[k = c*32 + kh*16 + (lane>>5)*8 + j][n' = nt*32 + (lane&31)]
// where nt 0,1 = w_gate cols 0..63 and nt 2,3 = w_noise cols 0..63.
__global__ __launch_bounds__(256)
void presplit_kernel(const float* __restrict__ wg, const float* __restrict__ wn,
                     _Float16* __restrict__ wsB)
{
    int gid  = blockIdx.x * 256 + threadIdx.x;   // 0..65535 = (fb, lane)
    int lane = gid & 63;
    int fb   = gid >> 6;          // 0..1023
    int nt   = fb & 3;
    int p    = (fb >> 2) & 1;
    int kh   = (fb >> 3) & 1;
    int c    = fb >> 4;
    const float* src = (nt < 2) ? (wg + nt * 32 + (lane & 31))
                                : (wn + (nt - 2) * 32 + (lane & 31));
    int kb = c * 32 + kh * 16 + ((lane >> 5) << 3);
    half8v hp;
    #pragma unroll
    for (int j = 0; j < 8; ++j) {
        float w = src[(size_t)(kb + j) * NEXP] * 65536.0f;
        _Float16 a = (_Float16)w;
        hp[j] = p ? (_Float16)(w - (float)a) : a;
    }
    *(half8v*)(wsB + (size_t)fb * 512 + lane * 8) = hp;
}

// ---- main kernel: 512 threads = 8 waves as (rg = w>>2, t = w&3).
// Wave tile: 32 rows (rg) x 32 cols of tile t (0=gate-lo,1=gate-hi,2=noise-lo,3=noise-hi).
__global__ __launch_bounds__(512, 4)
void routing_mfma(const float* __restrict__ x, const _Float16* __restrict__ wsB,
                  const float* __restrict__ noise, float* __restrict__ out)
{
    // 48 KB: [Bs: 2 x 16KB][Xs: 2 x 8KB]; whole region reused as epilogue scratch.
    __shared__ __align__(16) char smem[49152];
    _Float16* Bs = (_Float16*)smem;              // [2][8192] halfs
    float*    Xs = (float*)(smem + 32768);       // [2][2048] floats

    const int tid  = threadIdx.x;
    const int lane = tid & 63;
    const int w    = tid >> 6;          // 0..7
    const int rg   = w >> 2;            // row group (0,1)
    const int t    = w & 3;             // col tile
    const int m    = lane & 31;
    const int h    = lane >> 5;
    const int row0 = blockIdx.x * BM;

    f32x16 acc = {};

    // ---- staging: 3 DMA instrs per wave per chunk, all contiguous 1KB.
    // x source is pre-swizzled: LDS[r][slot] = x[r][slot ^ (r&7)] (16B slots).
    const int r7   = lane >> 3;                   // row within this wave's 8-row group
    const int ssrc = (lane & 7) ^ (r7 & 7);       // inverse-swizzled 16B slot
    const float* xsrc = x + (size_t)(row0 + w * 8 + r7) * DIMK + ssrc * 4;

    auto stage = [&](int c, int buf) {
        #pragma unroll
        for (int ii = 0; ii < 2; ++ii) {          // B: 16 x 1KB frag blocks / chunk
            int idx = w * 2 + ii;
            async_load16(wsB + ((size_t)c * 16 + idx) * 512 + lane * 8,
                         Bs + buf * 8192 + idx * 512);
        }
        // x: 8 rows x 128B per instr, 8 instrs cover the 64x32f chunk tile
        async_load16(xsrc + c * 32, Xs + buf * 2048 + w * 256);
    };

    stage(0, 0);
    stage(1, 1);
    __syncthreads();

    const int r   = rg * 32 + m;        // this lane's A-frag row
    const int rx7 = r & 7;

    for (int c = 0; c < NCH; ++c) {
        const int buf = c & 1;
        const float*    xrow = Xs + buf * 2048 + r * 32;
        const _Float16* bb   = Bs + buf * 8192 + t * 512 + lane * 8;

        // B frags (lane-linear 16B, conflict-free): idx t, t+4, t+8, t+12
        half8v bH0 = *(const half8v*)(bb);
        half8v bL0 = *(const half8v*)(bb + 2048);
        half8v bH1 = *(const half8v*)(bb + 4096);
        half8v bL1 = *(const half8v*)(bb + 6144);

        // x frags: logical slot = kh*4 + h*2 + q, stored at slot^ (r&7)
        float4 x00 = *(const float4*)(xrow + ((h * 2 + 0) ^ rx7) * 4);
        float4 x01 = *(const float4*)(xrow + ((h * 2 + 1) ^ rx7) * 4);
        float4 x10 = *(const float4*)(xrow + ((4 + h * 2 + 0) ^ rx7) * 4);
        float4 x11 = *(const float4*)(xrow + ((4 + h * 2 + 1) ^ rx7) * 4);

        // convert to split-fp16 planes (in registers, per kh)
        half8v aH0, aL0, aH1, aL1;
        {
            float f[8] = {x00.x, x00.y, x00.z, x00.w, x01.x, x01.y, x01.z, x01.w};
            #pragma unroll
            for (int j = 0; j < 8; ++j) {
                float v = f[j] * 1024.f;
                _Float16 a = (_Float16)v;
                aH0[j] = a; aL0[j] = (_Float16)(v - (float)a);
            }
        }
        {
            float f[8] = {x10.x, x10.y, x10.z, x10.w, x11.x, x11.y, x11.z, x11.w};
            #pragma unroll
            for (int j = 0; j < 8; ++j) {
                float v = f[j] * 1024.f;
                _Float16 a = (_Float16)v;
                aH1[j] = a; aL1[j] = (_Float16)(v - (float)a);
            }
        }

        // 3-pass split MFMA per kh (same op order as R9's refcheck-passed run)
        acc = __builtin_amdgcn_mfma_f32_32x32x16_f16(aH0, bH0, acc, 0, 0, 0);
        acc = __builtin_amdgcn_mfma_f32_32x32x16_f16(aH0, bL0, acc, 0, 0, 0);
        acc = __builtin_amdgcn_mfma_f32_32x32x16_f16(aL0, bH0, acc, 0, 0, 0);
        acc = __builtin_amdgcn_mfma_f32_32x32x16_f16(aH1, bH1, acc, 0, 0, 0);
        acc = __builtin_amdgcn_mfma_f32_32x32x16_f16(aH1, bL1, acc, 0, 0, 0);
        acc = __builtin_amdgcn_mfma_f32_32x32x16_f16(aL1, bH1, acc, 0, 0, 0);

        // One barrier/chunk: drains our ds_reads (lgkm) and chunk c+1's DMAs
        // (vmcnt0 -- issued a full chunk ago, so no stall), then it is safe
        // to overwrite buf with chunk c+2.
        __syncthreads();
        if (c + 2 < NCH) stage(c + 2, buf);
    }

    // ---- epilogue ----
    // 32x32 C/D layout: col = lane&31 (expert within tile),
    // row = (reg&3) + 8*(reg>>2) + 4*(lane>>5). Unscale by 2^-26.
    // Write scaled tiles into scratch (reuses staging LDS; last loop barrier
    // guarantees all reads are done), then per-row combine + top2 + scatter.
    const float s = 0x1p-26f;
    constexpr int SLD = 68;                 // 16B-aligned row stride (floats)
    float* scr = (float*)smem;              // [2 plane][64][SLD] = 34.8 KB
    {
        const int pl   = (t >> 1) * 64 * SLD;
        const int colb = (t & 1) * 32 + m;
        #pragma unroll
        for (int reg = 0; reg < 16; ++reg) {
            int rl = (reg & 3) + 8 * (reg >> 2) + 4 * h;     // 0..31
            scr[pl + (rg * 32 + rl) * SLD + colb] = acc[reg] * s;
        }
    }
    __syncthreads();

    {
        int rr = tid >> 3;           // 0..63: row within block
        int s8 = tid & 7;            // 8-expert segment
        const float* gp = scr + rr * SLD + s8 * 8;
        const float* np = scr + 64 * SLD + rr * SLD + s8 * 8;
        float4 g0 = *(const float4*)(gp);
        float4 g1 = *(const float4*)(gp + 4);
        float4 n0 = *(const float4*)(np);
        float4 n1 = *(const float4*)(np + 4);
        float4 z0 = *(const float4*)(noise + (size_t)(row0 + rr) * NEXP + s8 * 8);
        float4 z1 = *(const float4*)(noise + (size_t)(row0 + rr) * NEXP + s8 * 8 + 4);
        float gg[8] = {g0.x, g0.y, g0.z, g0.w, g1.x, g1.y, g1.z, g1.w};
        float nn[8] = {n0.x, n0.y, n0.z, n0.w, n1.x, n1.y, n1.z, n1.w};
        float zz[8] = {z0.x, z0.y, z0.z, z0.w, z1.x, z1.y, z1.z, z1.w};
        float v1 = -INFINITY, v2 = -INFINITY;
        int   i1 = 0x7ffffffe,  i2 = 0x7fffffff;
        #pragma unroll
        for (int j = 0; j < 8; ++j) {
            float nv = nn[j];
            float sp = fmaxf(nv, 0.f) + log1pf(expf(-fabsf(nv)));
            float vv = gg[j] + zz[j] * (sp + 0.01f);
            int   e  = s8 * 8 + j;
            if (gt_pair(vv, e, v1, i1)) { v2 = v1; i2 = i1; v1 = vv; i1 = e; }
            else if (gt_pair(vv, e, v2, i2)) { v2 = vv; i2 = e; }
        }
        #pragma unroll
        for (int mm = 1; mm <= 4; mm <<= 1) {    // butterfly over the 8-lane group
            float b1 = __shfl_xor(v1, mm); int ib1 = __shfl_xor(i1, mm);
            float b2 = __shfl_xor(v2, mm); int ib2 = __shfl_xor(i2, mm);
            if (gt_pair(b1, ib1, v1, i1)) {
                float o1 = v1; int oi1 = i1;
                v1 = b1; i1 = ib1;
                if (gt_pair(b2, ib2, o1, oi1)) { v2 = b2; i2 = ib2; }
                else                           { v2 = o1; i2 = oi1; }
            } else if (gt_pair(b1, ib1, v2, i2)) {
                v2 = b1; i2 = ib1;
            }
        }
        // all 8 lanes converge to the row's top2; softmax + scatter directly
        float te = expf(v2 - v1);     // <= 1
        float ga = 1.f / (1.f + te);
        float gb = te * ga;
        float* op = out + (size_t)(row0 + rr) * NEXP + s8 * 8;
        #pragma unroll
        for (int qq = 0; qq < 2; ++qq) {
            int e0 = s8 * 8 + qq * 4;
            float4 o;
            o.x = (e0 + 0 == i1) ? ga : ((e0 + 0 == i2) ? gb : 0.f);
            o.y = (e0 + 1 == i1) ? ga : ((e0 + 1 == i2) ? gb : 0.f);
            o.z = (e0 + 2 == i1) ? ga : ((e0 + 2 == i2) ? gb : 0.f);
            o.w = (e0 + 3 == i1) ? ga : ((e0 + 3 == i2) ? gb : 0.f);
            *(float4*)(op + qq * 4) = o;
        }
    }
}

extern "C" void kernel_launch(void* const* d_in, const int* in_sizes, int n_in,
                              void* d_out, int out_size, void* d_ws, size_t ws_size,
                              hipStream_t stream) {
    const float* x     = (const float*)d_in[0];
    const float* wg    = (const float*)d_in[1];
    const float* wn    = (const float*)d_in[2];
    const float* noise = (const float*)d_in[3];
    float* out = (float*)d_out;
    _Float16* wsB = (_Float16*)d_ws;   // needs 1024 * 1KB = 1 MB

    presplit_kernel<<<dim3(256), 256, 0, stream>>>(wg, wn, wsB);

    const int Brows = in_sizes[0] / DIMK;          // 32768
    dim3 grid(Brows / BM);                         // 512 blocks -> 2/CU, 16 waves/CU
    routing_mfma<<<grid, 512, 0, stream>>>(x, wsB, noise, out);
}